// Round 1
// baseline (91.071 us; speedup 1.0000x reference)
//
#include <hip/hip_runtime.h>

#define B_ 8
#define H_ 96
#define W_ 96
#define O_ 8
#define HW_ (H_ * W_)          // 9216
#define NT 512                 // threads per block (8 waves)
#define NPART ((NT / 64) * 8)  // 64 partials in LDS

// One block per (b,o). Each thread accumulates 60 structured sums
// S[ij][kl] = sum over pixels of X_ij * Q_kl, where
//   X = sum_r x_r x_r^T (3x3 sym, 6 unique), x_r = (wp0*a, wp1*c, wp0*du+wp1*dv)
//   Q = q q^T (4x4 sym, 10 unique), q = (p1,p2,p3,1)
// MtM(13x13) entry (r,c): r,c==9 -> 0; else r->(i,k), c->(j,l), value S[{i,j}][{k,l}].
__global__ __launch_bounds__(NT) void mtm_kernel(
    const float* __restrict__ obj,   // (B,H,W,O,3)
    const float* __restrict__ wpx,   // (B,H,W,O,4)
    const float* __restrict__ cam,   // (B,3,3)
    const float* __restrict__ ck,    // (B,2,2)
    float* __restrict__ out)         // (B,O,13,13)
{
    const int bo = blockIdx.x;       // b*8 + o
    const int b  = bo >> 3;
    const int o  = bo & 7;

    const float* cm = cam + b * 9;
    const float* k4 = ck  + b * 4;
    const float a   = -cm[0];          // -cm00
    const float c   = -cm[4];          // -cm11
    const float k00 = k4[0];
    const float k01 = k4[1];
    const float Bu  = k4[2] - cm[2];   // K10 - cm02
    const float Bv  = k4[3] - cm[5];   // K11 - cm12

    float acc[60];
#pragma unroll
    for (int s = 0; s < 60; ++s) acc[s] = 0.f;

    const int baseo = (b * HW_) * O_ + o;   // slot index base (fits int)

    for (int p = threadIdx.x; p < HW_; p += NT) {   // 18 iters exactly
        const int h = p / W_;
        const int w = p - h * W_;
        const int slot = baseo + p * O_;            // (b*HW+p)*8 + o

        const float* ob = obj + slot * 3;
        const float p1 = ob[0], p2 = ob[1], p3 = ob[2];
        const float4 wp = *(const float4*)(wpx + slot * 4);

        const float du = fmaf((float)w, k00, Bu);
        const float dv = fmaf((float)h, k01, Bv);

        const float x00 = wp.x * a;
        const float x01 = wp.y * c;
        const float x02 = fmaf(wp.x, du, wp.y * dv);
        const float x10 = wp.z * a;
        const float x11 = wp.w * c;
        const float x12 = fmaf(wp.z, du, wp.w * dv);

        float Xa[6];
        Xa[0] = fmaf(x00, x00, x10 * x10);
        Xa[1] = fmaf(x00, x01, x10 * x11);
        Xa[2] = fmaf(x00, x02, x10 * x12);
        Xa[3] = fmaf(x01, x01, x11 * x11);
        Xa[4] = fmaf(x01, x02, x11 * x12);
        Xa[5] = fmaf(x02, x02, x12 * x12);

        float Q[10];
        Q[0] = p1 * p1; Q[1] = p1 * p2; Q[2] = p1 * p3; Q[3] = p1;
        Q[4] = p2 * p2; Q[5] = p2 * p3; Q[6] = p2;
        Q[7] = p3 * p3; Q[8] = p3;
        Q[9] = 1.f;

#pragma unroll
        for (int ij = 0; ij < 6; ++ij) {
#pragma unroll
            for (int kl = 0; kl < 10; ++kl)
                acc[ij * 10 + kl] = fmaf(Xa[ij], Q[kl], acc[ij * 10 + kl]);
        }
    }

    // Partial wave reduce over lane bits 3,4,5 -> lanes 0..7 hold distinct partials
#pragma unroll
    for (int s = 0; s < 60; ++s) {
        float v = acc[s];
        v += __shfl_xor(v, 8,  64);
        v += __shfl_xor(v, 16, 64);
        v += __shfl_xor(v, 32, 64);
        acc[s] = v;
    }

    __shared__ float lds[NPART * 60];
    __shared__ float S[60];
    const int lane = threadIdx.x & 63;
    const int wave = threadIdx.x >> 6;
    if (lane < 8) {
#pragma unroll
        for (int s = 0; s < 60; ++s)
            lds[(wave * 8 + lane) * 60 + s] = acc[s];
    }
    __syncthreads();

    if (threadIdx.x < 60) {
        float v = 0.f;
#pragma unroll
        for (int t = 0; t < NPART; ++t) v += lds[t * 60 + threadIdx.x];
        S[threadIdx.x] = v;
    }
    __syncthreads();

    // Scatter 60 sums -> 169 outputs (row/col 9 are structurally zero)
    for (int t = threadIdx.x; t < 169; t += NT) {
        const int r = t / 13;
        const int cc = t - r * 13;
        float val = 0.f;
        if (r != 9 && cc != 9) {
            int i, k, j, l;
            if (r < 9)  { i = r / 3;  k = r - i * 3; } else { i = r - 10;  k = 3; }
            if (cc < 9) { j = cc / 3; l = cc - j * 3; } else { j = cc - 10; l = 3; }
            const int ii = i < j ? i : j, jj = i < j ? j : i;
            const int kk = k < l ? k : l, ll = k < l ? l : k;
            const int ijIdx = ii * (5 - ii) / 2 + jj;   // 0..5
            const int klIdx = kk * (7 - kk) / 2 + ll;   // 0..9
            val = S[ijIdx * 10 + klIdx];
        }
        out[bo * 169 + t] = val;
    }
}

extern "C" void kernel_launch(void* const* d_in, const int* in_sizes, int n_in,
                              void* d_out, int out_size, void* d_ws, size_t ws_size,
                              hipStream_t stream) {
    const float* obj = (const float*)d_in[0];
    const float* wpx = (const float*)d_in[1];
    const float* cam = (const float*)d_in[2];
    const float* ck  = (const float*)d_in[3];
    float* out = (float*)d_out;

    mtm_kernel<<<dim3(B_ * O_), dim3(NT), 0, stream>>>(obj, wpx, cam, ck, out);
}

// Round 2
// 84.179 us; speedup vs baseline: 1.0819x; 1.0819x over previous
//
#include <hip/hip_runtime.h>

#define B_ 8
#define H_ 96
#define W_ 96
#define O_ 8
#define HW_ (H_ * W_)          // 9216
#define NT 512                 // threads per block (8 waves)
#define NCH 72                 // HW chunks -> grid = B_*NCH = 576 blocks
#define PPB (HW_ / NCH)        // 128 pixels per block
#define ITERS (PPB / 64)       // 2 compute iterations (64 pixels x 8 o per iter)

// Block covers (b, pixel-chunk) for ALL 8 o's. Thread t: o = t&7, pg = t>>3.
// Loads are fully coalesced: obj 12 B/lane, wp 16 B/lane contiguous.
// Per-thread accumulates 60 structured sums S[ij][kl] (see round-0 derivation:
// MtM = sum_px (sum_r x_r x_r^T) (x) (q q^T), 6 unique X * 10 unique Q).
// Cross-block combine: atomicAdd into pre-zeroed d_out.
__global__ __launch_bounds__(NT) void mtm_kernel(
    const float* __restrict__ obj,   // (B,H,W,O,3)
    const float* __restrict__ wpx,   // (B,H,W,O,4)
    const float* __restrict__ cam,   // (B,3,3)
    const float* __restrict__ ck,    // (B,2,2)
    float* __restrict__ out)         // (B,O,13,13) -- zeroed before launch
{
    const int chunk = blockIdx.x;    // 0..NCH-1
    const int b     = blockIdx.y;    // 0..B_-1

    const float* cm = cam + b * 9;
    const float* k4 = ck  + b * 4;
    const float a   = -cm[0];
    const float c   = -cm[4];
    const float k00 = k4[0];
    const float k01 = k4[1];
    const float Bu  = k4[2] - cm[2];
    const float Bv  = k4[3] - cm[5];

    const int o  = threadIdx.x & 7;
    const int pg = threadIdx.x >> 3;          // 0..63 pixel-group within block

    float acc[60];
#pragma unroll
    for (int s = 0; s < 60; ++s) acc[s] = 0.f;

#pragma unroll
    for (int it = 0; it < ITERS; ++it) {
        const int p = chunk * PPB + it * 64 + pg;   // pixel index in HW
        const int h = p / W_;
        const int w = p - h * W_;
        const int slot = (b * HW_ + p) * O_ + o;

        const float* ob = obj + (size_t)slot * 3;
        const float p1 = ob[0], p2 = ob[1], p3 = ob[2];
        const float4 wp = *(const float4*)(wpx + (size_t)slot * 4);

        const float du = fmaf((float)w, k00, Bu);
        const float dv = fmaf((float)h, k01, Bv);

        const float x00 = wp.x * a;
        const float x01 = wp.y * c;
        const float x02 = fmaf(wp.x, du, wp.y * dv);
        const float x10 = wp.z * a;
        const float x11 = wp.w * c;
        const float x12 = fmaf(wp.z, du, wp.w * dv);

        float Xa[6];
        Xa[0] = fmaf(x00, x00, x10 * x10);
        Xa[1] = fmaf(x00, x01, x10 * x11);
        Xa[2] = fmaf(x00, x02, x10 * x12);
        Xa[3] = fmaf(x01, x01, x11 * x11);
        Xa[4] = fmaf(x01, x02, x11 * x12);
        Xa[5] = fmaf(x02, x02, x12 * x12);

        float Q[10];
        Q[0] = p1 * p1; Q[1] = p1 * p2; Q[2] = p1 * p3; Q[3] = p1;
        Q[4] = p2 * p2; Q[5] = p2 * p3; Q[6] = p2;
        Q[7] = p3 * p3; Q[8] = p3;
        Q[9] = 1.f;

#pragma unroll
        for (int ij = 0; ij < 6; ++ij) {
#pragma unroll
            for (int kl = 0; kl < 10; ++kl)
                acc[ij * 10 + kl] = fmaf(Xa[ij], Q[kl], acc[ij * 10 + kl]);
        }
    }

    // In-wave reduce over pixel-groups: lanes with equal o are lane = o + 8j.
#pragma unroll
    for (int s = 0; s < 60; ++s) {
        float v = acc[s];
        v += __shfl_xor(v, 8,  64);
        v += __shfl_xor(v, 16, 64);
        v += __shfl_xor(v, 32, 64);
        acc[s] = v;
    }

    __shared__ float lds[64 * 60];   // (wave*8+o) x 60
    __shared__ float Sf[8 * 60];     // per-o final sums
    const int lane = threadIdx.x & 63;
    const int wave = threadIdx.x >> 6;
    if (lane < 8) {
#pragma unroll
        for (int s = 0; s < 60; ++s)
            lds[(wave * 8 + lane) * 60 + s] = acc[s];
    }
    __syncthreads();

    if (threadIdx.x < 480) {         // 8 o x 60 s
        const int oo = threadIdx.x / 60;
        const int ss = threadIdx.x - oo * 60;
        float v = 0.f;
#pragma unroll
        for (int w = 0; w < 8; ++w) v += lds[(w * 8 + oo) * 60 + ss];
        Sf[oo * 60 + ss] = v;
    }
    __syncthreads();

    // Scatter-accumulate 8 x 169 outputs (skip structurally-zero row/col 9).
    for (int t = threadIdx.x; t < 8 * 169; t += NT) {
        const int oo = t / 169;
        const int e  = t - oo * 169;
        const int r  = e / 13;
        const int cc = e - r * 13;
        if (r == 9 || cc == 9) continue;
        int i, k, j, l;
        if (r < 9)  { i = r / 3;  k = r - i * 3; } else { i = r - 10;  k = 3; }
        if (cc < 9) { j = cc / 3; l = cc - j * 3; } else { j = cc - 10; l = 3; }
        const int ii = i < j ? i : j, jj = i < j ? j : i;
        const int kk = k < l ? k : l, ll = k < l ? l : k;
        const int ijIdx = ii * (5 - ii) / 2 + jj;   // 0..5
        const int klIdx = kk * (7 - kk) / 2 + ll;   // 0..9
        atomicAdd(out + ((size_t)(b * O_ + oo) * 169 + e),
                  Sf[oo * 60 + ijIdx * 10 + klIdx]);
    }
}

extern "C" void kernel_launch(void* const* d_in, const int* in_sizes, int n_in,
                              void* d_out, int out_size, void* d_ws, size_t ws_size,
                              hipStream_t stream) {
    const float* obj = (const float*)d_in[0];
    const float* wpx = (const float*)d_in[1];
    const float* cam = (const float*)d_in[2];
    const float* ck  = (const float*)d_in[3];
    float* out = (float*)d_out;

    hipMemsetAsync(out, 0, (size_t)out_size * sizeof(float), stream);
    mtm_kernel<<<dim3(NCH, B_), dim3(NT), 0, stream>>>(obj, wpx, cam, ck, out);
}